// Round 1
// baseline (454.807 us; speedup 1.0000x reference)
//
#include <hip/hip_runtime.h>
#include <hip/hip_bf16.h>

// ---------------------------------------------------------------------------
// MultiHeadAttention: x[2,2048,2048] f32, W_qkv[6144,2048], W_out[2048,2048]
// out = MHA(x) in fp32. Internally bf16 MFMA with fp32 accumulation.
// ---------------------------------------------------------------------------

typedef short bf16x8 __attribute__((ext_vector_type(8)));
typedef float f32x4  __attribute__((ext_vector_type(4)));

#define MFMA(a, b, c) __builtin_amdgcn_mfma_f32_16x16x32_bf16((a), (b), (c), 0, 0, 0)

#define GLDS16(gp, lp) __builtin_amdgcn_global_load_lds(                        \
    (const __attribute__((address_space(1))) void*)(gp),                        \
    (__attribute__((address_space(3))) void*)(lp), 16, 0, 0)

static __device__ __forceinline__ unsigned short f2bf(float f) {
    __hip_bfloat16 h = __float2bfloat16(f);
    return *reinterpret_cast<unsigned short*>(&h);
}

// ---------------- fp32 -> bf16 convert (vectorized) ------------------------
__global__ __launch_bounds__(256) void cvt_f32_bf16(const float* __restrict__ in,
                                                    unsigned short* __restrict__ out,
                                                    int n4) {
    int i = blockIdx.x * 256 + threadIdx.x;
    if (i < n4) {
        float4 v = reinterpret_cast<const float4*>(in)[i];
        ushort4 o;
        o.x = f2bf(v.x); o.y = f2bf(v.y); o.z = f2bf(v.z); o.w = f2bf(v.w);
        reinterpret_cast<ushort4*>(out)[i] = o;
    }
}

// ---------------- GEMM: C[M,N] = A[M,K] * W[N,K]^T (both K-contiguous) ------
// m97 structure: 128x128 tile, BK=32, 4 waves (2x2 of 64x64), global_load_lds.
template <bool BF16OUT>
__global__ __launch_bounds__(256) void gemm_bt(const unsigned short* __restrict__ A,
                                               const unsigned short* __restrict__ W,
                                               void* __restrict__ Cout,
                                               int M, int N, int K) {
    __shared__ unsigned short As[128 * 32];
    __shared__ unsigned short Bs[128 * 32];
    const int tid = threadIdx.x;
    const int w = tid >> 6, lane = tid & 63;
    const int fr = lane & 15, fq = lane >> 4;
    const int m0 = blockIdx.y * 128, n0 = blockIdx.x * 128;
    const int wr = w >> 1, wc = w & 1;

    f32x4 acc[4][4];
#pragma unroll
    for (int a = 0; a < 4; a++)
#pragma unroll
        for (int b = 0; b < 4; b++) acc[a][b] = f32x4{0.f, 0.f, 0.f, 0.f};

    const int srow = w * 16 + (lane >> 2);   // staging row within 64-row chunk
    const int scol = (lane & 3) * 8;         // staging col (8 bf16 = 16B)

    for (int kt = 0; kt < K; kt += 32) {
        __syncthreads();
#pragma unroll
        for (int it = 0; it < 2; ++it) {
            const unsigned short* ga = A + (size_t)(m0 + it * 64 + srow) * K + kt + scol;
            unsigned short* la = As + (it * 64 + w * 16) * 32;   // wave-uniform base
            GLDS16(ga, la);
            const unsigned short* gb = W + (size_t)(n0 + it * 64 + srow) * K + kt + scol;
            unsigned short* lb = Bs + (it * 64 + w * 16) * 32;
            GLDS16(gb, lb);
        }
        asm volatile("s_waitcnt vmcnt(0)" ::: "memory");
        __syncthreads();

        bf16x8 af[4], bfr[4];
#pragma unroll
        for (int mi = 0; mi < 4; mi++)
            af[mi] = *reinterpret_cast<const bf16x8*>(As + (wr * 64 + mi * 16 + fr) * 32 + fq * 8);
#pragma unroll
        for (int ni = 0; ni < 4; ni++)
            bfr[ni] = *reinterpret_cast<const bf16x8*>(Bs + (wc * 64 + ni * 16 + fr) * 32 + fq * 8);
#pragma unroll
        for (int mi = 0; mi < 4; mi++)
#pragma unroll
            for (int ni = 0; ni < 4; ni++)
                acc[mi][ni] = MFMA(af[mi], bfr[ni], acc[mi][ni]);
    }

    // epilogue: C/D layout col=lane&15, row=(lane>>4)*4+reg  [verified m89/m91]
#pragma unroll
    for (int mi = 0; mi < 4; mi++) {
#pragma unroll
        for (int i = 0; i < 4; i++) {
            const int row = m0 + wr * 64 + mi * 16 + fq * 4 + i;
            const size_t base = (size_t)row * N + n0 + wc * 64 + fr;
#pragma unroll
            for (int ni = 0; ni < 4; ni++) {
                if (BF16OUT)
                    ((unsigned short*)Cout)[base + ni * 16] = f2bf(acc[mi][ni][i]);
                else
                    ((float*)Cout)[base + ni * 16] = acc[mi][ni][i];
            }
        }
    }
}

// ---------------- V transpose: qkv V-part [4096][2048] -> vT[2][2048][2048] --
// vT[(b*2048 + h*128+dk)*2048 + s] = qkv[(b*2048+s)*6144 + 4096 + h*128+dk]
__global__ __launch_bounds__(256) void transpose_v(const unsigned short* __restrict__ qkv,
                                                   unsigned short* __restrict__ vT) {
    __shared__ unsigned short t[32][33];
    const int b = blockIdx.z, ts = blockIdx.x, tu = blockIdx.y;
    const int i = threadIdx.x >> 5, j = threadIdx.x & 31;
#pragma unroll
    for (int ii = 0; ii < 4; ++ii) {
        const int row = i + ii * 8;  // s-local
        t[row][j] = qkv[(size_t)(b * 2048 + ts * 32 + row) * 6144 + 4096 + tu * 32 + j];
    }
    __syncthreads();
#pragma unroll
    for (int ii = 0; ii < 4; ++ii) {
        const int row = i + ii * 8;  // u-local
        vT[(size_t)(b * 2048 + tu * 32 + row) * 2048 + ts * 32 + j] = t[j][row];
    }
}

// ---------------- Flash attention, causal, wave-independent -----------------
// Each wave owns 16 q-rows of one (b,h). KVBLK=32 (two 16-col score tiles).
// K fragments from qkv (K rows are K-contiguous), V fragments from vT
// (dk rows are kv-contiguous). P transposed via per-wave LDS (stride 40).
#define SM_SCALE 0.08838834764831845f

__global__ __launch_bounds__(256) void attn_fwd(const unsigned short* __restrict__ qkv,
                                                const unsigned short* __restrict__ vT,
                                                unsigned short* __restrict__ ao) {
    __shared__ __align__(16) unsigned short Ps[4][16 * 40];
    const int tid = threadIdx.x;
    const int w = tid >> 6, lane = tid & 63;
    const int fr = lane & 15, fq = lane >> 4;
    const int gw = blockIdx.x * 4 + w;
    const int bh = gw & 31;            // waves in a block span 4 different (b,h)
    const int qi = 127 - (gw >> 5);    // heavy (large q0) tiles dispatched first
    const int b = bh >> 4, h = bh & 15;
    const int q0 = qi * 16;

    const unsigned short* Qb = qkv + (size_t)b * 2048 * 6144 + h * 128;
    const unsigned short* Kb = qkv + (size_t)b * 2048 * 6144 + (16 + h) * 128;
    const unsigned short* Vb = vT + (size_t)bh * 128 * 2048;

    bf16x8 qf[4];
    {
        const unsigned short* qr = Qb + (size_t)(q0 + fr) * 6144 + fq * 8;
#pragma unroll
        for (int c = 0; c < 4; c++) qf[c] = *reinterpret_cast<const bf16x8*>(qr + c * 32);
    }

    f32x4 acc[8];
#pragma unroll
    for (int f = 0; f < 8; f++) acc[f] = f32x4{0.f, 0.f, 0.f, 0.f};
    float m_r[4], l_r[4];
#pragma unroll
    for (int i = 0; i < 4; i++) { m_r[i] = -__builtin_inff(); l_r[i] = 0.f; }

    const int nb = (q0 >> 5) + 1;
    unsigned short* Pw = &Ps[w][0];

    for (int kb = 0; kb < nb; ++kb) {
        const int k0 = kb * 32;
        // K fragments: B-operand col = lane&15 (kv), k = (lane>>4)*8+j (kdim)
        bf16x8 kf[2][4];
#pragma unroll
        for (int t2 = 0; t2 < 2; t2++) {
            const unsigned short* kr = Kb + (size_t)(k0 + t2 * 16 + fr) * 6144 + fq * 8;
#pragma unroll
            for (int c = 0; c < 4; c++) kf[t2][c] = *reinterpret_cast<const bf16x8*>(kr + c * 32);
        }
        f32x4 s0 = f32x4{0.f, 0.f, 0.f, 0.f}, s1 = f32x4{0.f, 0.f, 0.f, 0.f};
#pragma unroll
        for (int c = 0; c < 4; c++) {
            s0 = MFMA(qf[c], kf[0][c], s0);
            s1 = MFMA(qf[c], kf[1][c], s1);
        }
        // V fragments: B-operand col = dk = f*16+fr, k = kv = fq*8+j
        bf16x8 vf[8];
#pragma unroll
        for (int f = 0; f < 8; f++)
            vf[f] = *reinterpret_cast<const bf16x8*>(Vb + (size_t)(f * 16 + fr) * 2048 + k0 + fq * 8);

        const bool last = (kb == nb - 1);
        float p0s[4], p1s[4];
#pragma unroll
        for (int i = 0; i < 4; i++) {
            const int qrow = q0 + fq * 4 + i;
            float a0 = s0[i] * SM_SCALE, a1 = s1[i] * SM_SCALE;
            if (last) {
                if (k0 + fr > qrow) a0 = -__builtin_inff();
                if (k0 + 16 + fr > qrow) a1 = -__builtin_inff();
            }
            float v = fmaxf(a0, a1);
            v = fmaxf(v, __shfl_xor(v, 1, 64));
            v = fmaxf(v, __shfl_xor(v, 2, 64));
            v = fmaxf(v, __shfl_xor(v, 4, 64));
            v = fmaxf(v, __shfl_xor(v, 8, 64));
            const float mn = fmaxf(m_r[i], v);
            const float corr = __expf(m_r[i] - mn);
            const float p0 = __expf(a0 - mn);
            const float p1 = __expf(a1 - mn);
            float su = p0 + p1;
            su += __shfl_xor(su, 1, 64);
            su += __shfl_xor(su, 2, 64);
            su += __shfl_xor(su, 4, 64);
            su += __shfl_xor(su, 8, 64);
            l_r[i] = l_r[i] * corr + su;
            m_r[i] = mn;
#pragma unroll
            for (int f = 0; f < 8; f++) acc[f][i] *= corr;
            p0s[i] = p0; p1s[i] = p1;
        }
        // P -> per-wave LDS (C-layout in, A-layout out). Stride 40 elems = 80B.
#pragma unroll
        for (int i = 0; i < 4; i++) {
            Pw[(fq * 4 + i) * 40 + fr] = f2bf(p0s[i]);
            Pw[(fq * 4 + i) * 40 + 16 + fr] = f2bf(p1s[i]);
        }
        bf16x8 pa = *reinterpret_cast<const bf16x8*>(Pw + fr * 40 + fq * 8);
#pragma unroll
        for (int f = 0; f < 8; f++) acc[f] = MFMA(pa, vf[f], acc[f]);
    }

    // epilogue: normalize and store bf16 [4096][2048]
#pragma unroll
    for (int f = 0; f < 8; f++) {
#pragma unroll
        for (int i = 0; i < 4; i++) {
            const int qrow = q0 + fq * 4 + i;
            const float o = acc[f][i] / l_r[i];
            ao[(size_t)(b * 2048 + qrow) * 2048 + h * 128 + f * 16 + fr] = f2bf(o);
        }
    }
}

// ---------------------------------------------------------------------------
extern "C" void kernel_launch(void* const* d_in, const int* in_sizes, int n_in,
                              void* d_out, int out_size, void* d_ws, size_t ws_size,
                              hipStream_t stream) {
    const float* x    = (const float*)d_in[0];
    const float* Wqkv = (const float*)d_in[1];
    const float* Wout = (const float*)d_in[2];
    float* out = (float*)d_out;

    // Workspace layout (96 MB), regions reused across phases:
    //   [0,16M):   xb (bf16 x), later reused as attnb
    //   [16M,40M): wqkvb (24M), later reused as vT (16M)
    //   [40M,48M): woutb
    //   [48M,96M): qkvb (bf16 [4096][6144])
    char* ws = (char*)d_ws;
    unsigned short* xb    = (unsigned short*)(ws);
    unsigned short* wqkvb = (unsigned short*)(ws + (size_t)(16 << 20));
    unsigned short* woutb = (unsigned short*)(ws + (size_t)(40 << 20));
    unsigned short* qkvb  = (unsigned short*)(ws + (size_t)(48 << 20));
    unsigned short* vTb   = (unsigned short*)(ws + (size_t)(16 << 20)); // over wqkvb
    unsigned short* attnb = (unsigned short*)(ws);                      // over xb

    cvt_f32_bf16<<<8192, 256, 0, stream>>>(x, xb, 2097152);
    cvt_f32_bf16<<<12288, 256, 0, stream>>>(Wqkv, wqkvb, 3145728);
    cvt_f32_bf16<<<4096, 256, 0, stream>>>(Wout, woutb, 1048576);

    // qkv = x @ W_qkv^T : M=4096, N=6144, K=2048, bf16 out
    gemm_bt<true><<<dim3(48, 32), 256, 0, stream>>>(xb, wqkvb, qkvb, 4096, 6144, 2048);

    // vT[b][h*128+dk][s] = V[b][s][h*128+dk]  (wqkvb dead after the GEMM)
    transpose_v<<<dim3(64, 64, 2), 256, 0, stream>>>(qkvb, vTb);

    // causal flash attention -> attnb (bf16 [4096][2048])  (xb dead now)
    attn_fwd<<<1024, 256, 0, stream>>>(qkvb, vTb, attnb);

    // out = attnb @ W_out^T : M=4096, N=2048, K=2048, fp32 out
    gemm_bt<false><<<dim3(16, 32), 256, 0, stream>>>(attnb, woutb, out, 4096, 2048, 2048);
}